// Round 2
// baseline (1237.628 us; speedup 1.0000x reference)
//
#include <hip/hip_runtime.h>

// Problem constants (fixed by the reference):
constexpr int B = 4, C = 3, F = 80, N = 256;
constexpr int H = 1024, W = 2048;
constexpr int HW = H * W;          // 2,097,152 pixels
constexpr int PLANE = F * N * N;   // 5,242,880 floats per (b,c) plane
constexpr int BC = B * C;          // 12 planes

// One thread per output pixel (h,w). Index math + weights computed once,
// reused across all 12 (b,c) planes. Nontemporal stores for the write-once
// output so L2/L3 capacity stays dedicated to the x gather working set.
__global__ __launch_bounds__(256) void tan2equi_kernel(
    const float* __restrict__ x,     // [B,C,F,N,N]
    const int*   __restrict__ quad,  // [H,W]
    const float* __restrict__ uv,    // [H,W,2]
    float*       __restrict__ out)   // [B,C,H,W]
{
    const int p = blockIdx.x * blockDim.x + threadIdx.x;
    if (p >= HW) return;

    // Coalesced 8B load of (u,v)
    const float2 uvp = reinterpret_cast<const float2*>(uv)[p];
    const float u = uvp.x;
    const float v = uvp.y;
    const int   q = quad[p];

    const float u0f = floorf(u);
    const float v0f = floorf(v);
    const float du = u - u0f;
    const float dv = v - v0f;

    int u0 = (int)u0f; u0 = min(max(u0, 0), N - 1);
    int u1 = min(u0 + 1, N - 1);
    int v0 = (int)v0f; v0 = min(max(v0, 0), N - 1);
    int v1 = min(v0 + 1, N - 1);

    const float w00 = (1.0f - du) * (1.0f - dv);
    const float w01 = du * (1.0f - dv);
    const float w10 = (1.0f - du) * dv;
    const float w11 = du * dv;

    const int base = q * (N * N);
    const int i00 = base + v0 * N + u0;
    const int i01 = base + v0 * N + u1;
    const int i10 = base + v1 * N + u0;
    const int i11 = base + v1 * N + u1;

    const float* xp = x;
    #pragma unroll
    for (int bc = 0; bc < BC; ++bc) {
        const float r = xp[i00] * w00
                      + xp[i01] * w01
                      + xp[i10] * w10
                      + xp[i11] * w11;
        __builtin_nontemporal_store(r, out + bc * HW + p);
        xp += PLANE;
    }
}

extern "C" void kernel_launch(void* const* d_in, const int* in_sizes, int n_in,
                              void* d_out, int out_size, void* d_ws, size_t ws_size,
                              hipStream_t stream) {
    const float* x    = (const float*)d_in[0];
    const int*   quad = (const int*)d_in[1];
    const float* uv   = (const float*)d_in[2];
    float*       out  = (float*)d_out;

    const int threads = 256;
    const int blocks  = (HW + threads - 1) / threads;  // 8192 blocks
    tan2equi_kernel<<<blocks, threads, 0, stream>>>(x, quad, uv, out);
}